// Round 1
// baseline (328.441 us; speedup 1.0000x reference)
//
#include <hip/hip_runtime.h>
#include <math.h>

#define BROWS 4096
#define CCOLS 32000
#define NVEC  (CCOLS / 4)   // 8000 float4 per row
#define EPSF  1e-10f
#define NTHREADS 256

__global__ __launch_bounds__(NTHREADS) void gumbel_onehot_kernel(
    const float* __restrict__ logits,
    const float* __restrict__ u,
    float* __restrict__ out)
{
    const int row = blockIdx.x;
    const int tid = threadIdx.x;
    const size_t base = (size_t)row * CCOLS;

    const float4* __restrict__ lg4 = (const float4*)(logits + base);
    const float4* __restrict__ uu4 = (const float4*)(u + base);

    float best = -__builtin_inff();
    int besti = 0;

    // z = logits + gumbel, gumbel = -log(EPS - log(u + EPS)), tau = 1
    for (int i = tid; i < NVEC; i += NTHREADS) {
        float4 l  = lg4[i];
        float4 uv = uu4[i];
        float z;
        z = l.x - logf(EPSF - logf(uv.x + EPSF));
        if (z > best) { best = z; besti = 4 * i + 0; }
        z = l.y - logf(EPSF - logf(uv.y + EPSF));
        if (z > best) { best = z; besti = 4 * i + 1; }
        z = l.z - logf(EPSF - logf(uv.z + EPSF));
        if (z > best) { best = z; besti = 4 * i + 2; }
        z = l.w - logf(EPSF - logf(uv.w + EPSF));
        if (z > best) { best = z; besti = 4 * i + 3; }
    }

    // wave-64 reduction, first-index tie-break (jnp.argmax semantics)
    for (int off = 32; off > 0; off >>= 1) {
        float ov = __shfl_down(best, off, 64);
        int   oi = __shfl_down(besti, off, 64);
        if (ov > best || (ov == best && oi < besti)) { best = ov; besti = oi; }
    }

    __shared__ float sval[NTHREADS / 64];
    __shared__ int   sidx[NTHREADS / 64];
    __shared__ int   swin;
    const int lane = tid & 63;
    const int wv   = tid >> 6;
    if (lane == 0) { sval[wv] = best; sidx[wv] = besti; }
    __syncthreads();
    if (tid == 0) {
        float bv = sval[0]; int bi = sidx[0];
        #pragma unroll
        for (int w = 1; w < NTHREADS / 64; ++w) {
            float v = sval[w]; int ii = sidx[w];
            if (v > bv || (v == bv && ii < bi)) { bv = v; bi = ii; }
        }
        swin = bi;
    }
    __syncthreads();

    const int win = swin;
    const int q  = win >> 2;
    const int cc = win & 3;

    // stream the one-hot row: zeros everywhere, 1.0f at the winner
    float4* __restrict__ o4 = (float4*)(out + base);
    for (int i = tid; i < NVEC; i += NTHREADS) {
        float4 v = make_float4(0.f, 0.f, 0.f, 0.f);
        if (i == q) (&v.x)[cc] = 1.0f;
        o4[i] = v;
    }
}

extern "C" void kernel_launch(void* const* d_in, const int* in_sizes, int n_in,
                              void* d_out, int out_size, void* d_ws, size_t ws_size,
                              hipStream_t stream) {
    const float* logits = (const float*)d_in[0];
    const float* u      = (const float*)d_in[1];
    float* out          = (float*)d_out;
    gumbel_onehot_kernel<<<BROWS, NTHREADS, 0, stream>>>(logits, u, out);
}

// Round 3
// 283.680 us; speedup vs baseline: 1.1578x; 1.1578x over previous
//
#include <hip/hip_runtime.h>
#include <math.h>

#define BROWS 4096
#define CCOLS 32000
#define NVEC  (CCOLS / 4)   // 8000 float4 per row
#define EPSF  1e-10f
#define LN2F  0.69314718055994530942f
#define NTHREADS 256

typedef float f32x4 __attribute__((ext_vector_type(4)));

__global__ __launch_bounds__(NTHREADS) void gumbel_onehot_kernel(
    const float* __restrict__ logits,
    const float* __restrict__ u,
    float* __restrict__ out)
{
    const int row = blockIdx.x;
    const int tid = threadIdx.x;
    const size_t base = (size_t)row * CCOLS;

    const f32x4* __restrict__ lg4 = (const f32x4*)(logits + base);
    const f32x4* __restrict__ uu4 = (const f32x4*)(u + base);

    float best = -__builtin_inff();
    int besti = 0;

    // z = logits + gumbel, gumbel = -log(EPS - log(u + EPS)), tau = 1
    // log(x) = ln2 * log2(x), log2 via hardware v_log_f32 (~1 ulp of result)
    #pragma unroll 4
    for (int i = tid; i < NVEC; i += NTHREADS) {
        f32x4 l  = __builtin_nontemporal_load(&lg4[i]);
        f32x4 uv = __builtin_nontemporal_load(&uu4[i]);
        #pragma unroll
        for (int c = 0; c < 4; ++c) {
            float t = __builtin_fmaf(-LN2F, __log2f(uv[c] + EPSF), EPSF);
            float z = __builtin_fmaf(-LN2F, __log2f(t), l[c]);
            if (z > best) { best = z; besti = 4 * i + c; }
        }
    }

    // wave-64 reduction, first-index tie-break (jnp.argmax semantics)
    for (int off = 32; off > 0; off >>= 1) {
        float ov = __shfl_down(best, off, 64);
        int   oi = __shfl_down(besti, off, 64);
        if (ov > best || (ov == best && oi < besti)) { best = ov; besti = oi; }
    }

    __shared__ float sval[NTHREADS / 64];
    __shared__ int   sidx[NTHREADS / 64];
    __shared__ int   swin;
    const int lane = tid & 63;
    const int wv   = tid >> 6;
    if (lane == 0) { sval[wv] = best; sidx[wv] = besti; }
    __syncthreads();
    if (tid == 0) {
        float bv = sval[0]; int bi = sidx[0];
        #pragma unroll
        for (int w = 1; w < NTHREADS / 64; ++w) {
            float v = sval[w]; int ii = sidx[w];
            if (v > bv || (v == bv && ii < bi)) { bv = v; bi = ii; }
        }
        swin = bi;
    }
    __syncthreads();

    const int win = swin;
    const int q  = win >> 2;
    const int cc = win & 3;

    // stream the one-hot row: zeros everywhere, 1.0f at the winner
    f32x4* __restrict__ o4 = (f32x4*)(out + base);
    #pragma unroll 4
    for (int i = tid; i < NVEC; i += NTHREADS) {
        f32x4 v = (f32x4)(0.f, 0.f, 0.f, 0.f);
        if (i == q) v[cc] = 1.0f;
        __builtin_nontemporal_store(v, &o4[i]);
    }
}

extern "C" void kernel_launch(void* const* d_in, const int* in_sizes, int n_in,
                              void* d_out, int out_size, void* d_ws, size_t ws_size,
                              hipStream_t stream) {
    const float* logits = (const float*)d_in[0];
    const float* u      = (const float*)d_in[1];
    float* out          = (float*)d_out;
    gumbel_onehot_kernel<<<BROWS, NTHREADS, 0, stream>>>(logits, u, out);
}

// Round 4
// 254.533 us; speedup vs baseline: 1.2904x; 1.1145x over previous
//
#include <hip/hip_runtime.h>
#include <math.h>

#define BROWS 4096
#define CCOLS 32000
#define NVEC  (CCOLS / 4)   // 8000 float4 per row
#define EPSF  1e-10f
#define LN2F  0.69314718055994530942f
#define NTHREADS 256

typedef float f32x4 __attribute__((ext_vector_type(4)));

// ---------- kernel A: per-row argmax of logits + gumbel (pure read) ----------
__global__ __launch_bounds__(NTHREADS) void argmax_kernel(
    const float* __restrict__ logits,
    const float* __restrict__ u,
    int* __restrict__ win)
{
    const int row = blockIdx.x;
    const int tid = threadIdx.x;
    const size_t base = (size_t)row * CCOLS;

    const f32x4* __restrict__ lg4 = (const f32x4*)(logits + base);
    const f32x4* __restrict__ uu4 = (const f32x4*)(u + base);

    float best = -__builtin_inff();
    int besti = 0;

    // z = logits - log(EPS - log(u + EPS)); log via hw v_log_f32
    #pragma unroll 4
    for (int i = tid; i < NVEC; i += NTHREADS) {
        f32x4 l  = __builtin_nontemporal_load(&lg4[i]);
        f32x4 uv = __builtin_nontemporal_load(&uu4[i]);
        #pragma unroll
        for (int c = 0; c < 4; ++c) {
            float t = __builtin_fmaf(-LN2F, __log2f(uv[c] + EPSF), EPSF);
            float z = __builtin_fmaf(-LN2F, __log2f(t), l[c]);
            if (z > best) { best = z; besti = 4 * i + c; }
        }
    }

    // wave-64 reduction, first-index tie-break (jnp.argmax semantics)
    for (int off = 32; off > 0; off >>= 1) {
        float ov = __shfl_down(best, off, 64);
        int   oi = __shfl_down(besti, off, 64);
        if (ov > best || (ov == best && oi < besti)) { best = ov; besti = oi; }
    }

    __shared__ float sval[NTHREADS / 64];
    __shared__ int   sidx[NTHREADS / 64];
    const int lane = tid & 63;
    const int wv   = tid >> 6;
    if (lane == 0) { sval[wv] = best; sidx[wv] = besti; }
    __syncthreads();
    if (tid == 0) {
        float bv = sval[0]; int bi = sidx[0];
        #pragma unroll
        for (int w = 1; w < NTHREADS / 64; ++w) {
            float v = sval[w]; int ii = sidx[w];
            if (v > bv || (v == bv && ii < bi)) { bv = v; bi = ii; }
        }
        win[row] = bi;
    }
}

// ---------- kernel B: one-hot writer (pure write, fillBuffer-like) ----------
__global__ __launch_bounds__(NTHREADS) void onehot_kernel(
    const int* __restrict__ win,
    float* __restrict__ out)
{
    const int row = blockIdx.x;
    const int w  = win[row];
    const int q  = w >> 2;
    const int cc = w & 3;
    f32x4* __restrict__ o4 = (f32x4*)(out + (size_t)row * CCOLS);
    #pragma unroll 4
    for (int i = threadIdx.x; i < NVEC; i += NTHREADS) {
        f32x4 v = (f32x4)(0.f, 0.f, 0.f, 0.f);
        if (i == q) v[cc] = 1.0f;
        __builtin_nontemporal_store(v, &o4[i]);
    }
}

// ---------- fallback: fused single kernel (if ws too small) ----------
__global__ __launch_bounds__(NTHREADS) void gumbel_onehot_fused(
    const float* __restrict__ logits,
    const float* __restrict__ u,
    float* __restrict__ out)
{
    const int row = blockIdx.x;
    const int tid = threadIdx.x;
    const size_t base = (size_t)row * CCOLS;
    const f32x4* __restrict__ lg4 = (const f32x4*)(logits + base);
    const f32x4* __restrict__ uu4 = (const f32x4*)(u + base);

    float best = -__builtin_inff();
    int besti = 0;
    #pragma unroll 4
    for (int i = tid; i < NVEC; i += NTHREADS) {
        f32x4 l  = __builtin_nontemporal_load(&lg4[i]);
        f32x4 uv = __builtin_nontemporal_load(&uu4[i]);
        #pragma unroll
        for (int c = 0; c < 4; ++c) {
            float t = __builtin_fmaf(-LN2F, __log2f(uv[c] + EPSF), EPSF);
            float z = __builtin_fmaf(-LN2F, __log2f(t), l[c]);
            if (z > best) { best = z; besti = 4 * i + c; }
        }
    }
    for (int off = 32; off > 0; off >>= 1) {
        float ov = __shfl_down(best, off, 64);
        int   oi = __shfl_down(besti, off, 64);
        if (ov > best || (ov == best && oi < besti)) { best = ov; besti = oi; }
    }
    __shared__ float sval[NTHREADS / 64];
    __shared__ int   sidx[NTHREADS / 64];
    __shared__ int   swin;
    const int lane = tid & 63;
    const int wv   = tid >> 6;
    if (lane == 0) { sval[wv] = best; sidx[wv] = besti; }
    __syncthreads();
    if (tid == 0) {
        float bv = sval[0]; int bi = sidx[0];
        #pragma unroll
        for (int w = 1; w < NTHREADS / 64; ++w) {
            float v = sval[w]; int ii = sidx[w];
            if (v > bv || (v == bv && ii < bi)) { bv = v; bi = ii; }
        }
        swin = bi;
    }
    __syncthreads();
    const int w  = swin;
    const int q  = w >> 2;
    const int cc = w & 3;
    f32x4* __restrict__ o4 = (f32x4*)(out + base);
    #pragma unroll 4
    for (int i = tid; i < NVEC; i += NTHREADS) {
        f32x4 v = (f32x4)(0.f, 0.f, 0.f, 0.f);
        if (i == q) v[cc] = 1.0f;
        __builtin_nontemporal_store(v, &o4[i]);
    }
}

extern "C" void kernel_launch(void* const* d_in, const int* in_sizes, int n_in,
                              void* d_out, int out_size, void* d_ws, size_t ws_size,
                              hipStream_t stream) {
    const float* logits = (const float*)d_in[0];
    const float* u      = (const float*)d_in[1];
    float* out          = (float*)d_out;

    if (ws_size >= BROWS * sizeof(int)) {
        int* win = (int*)d_ws;
        argmax_kernel<<<BROWS, NTHREADS, 0, stream>>>(logits, u, win);
        onehot_kernel<<<BROWS, NTHREADS, 0, stream>>>(win, out);
    } else {
        gumbel_onehot_fused<<<BROWS, NTHREADS, 0, stream>>>(logits, u, out);
    }
}